// Round 2
// baseline (68.695 us; speedup 1.0000x reference)
//
#include <hip/hip_runtime.h>

// Problem config (fixed by reference): B=64, H=2, N=512, K=64, M=16
constexpr int Bsz = 64;
constexpr int Hn  = 2;
constexpr int Np  = 512;
constexpr int Kk  = 64;
constexpr int Mm  = 16;

#define EPSf      1e-7f
#define MAXN      (1.0f - 1e-5f)
#define ATANH_MAX 6.1030338f   // atanh(1 - 1e-5)

// Index identity (from the reference's raw reshape (B,K*N,M)->(B,N,K,M)):
//   sums[b,k'] = sum_{k=0..63} sum_{p=0..7} tangent(point n = 64p + k', theta row k)
// Per-term: x = exp0(pad(dgm[n])) + theta[k]; only first 2 comps of exp0 nonzero.
//   r^2 = (e0+t0)^2 + (e1+t1)^2 + c_k,  c_k = sum_{m>=2} t_m^2
//   a = atanh(min(max(r,EPS),MAXN)) / max(r,EPS)
//   tangent = a * x   (x_m = t_m for m>=2 -> per-lane partial is (S0, S1, A*t_m))
// Final exp0(log0(s)) collapses: y = s if |s| < atanh(MAXN), else ATANH_MAX * s/|s|.
__global__ __launch_bounds__(256) void PManifold_kernel(
    const float* __restrict__ inp,    // (B,H,N,2) fp32
    const float* __restrict__ theta,  // (H,K,M)  fp32
    float* __restrict__ out)          // (B,H,K,M) fp32
{
    const int tid  = threadIdx.x;
    const int lane = tid & 63;                  // = theta row k
    const int wav  = tid >> 6;
    const int g    = blockIdx.x * 4 + wav;      // global wave id in [0, B*H*K)
    const int kp   = g & 63;                    // output chart index k'
    const int bh   = g >> 6;                    // b*H + h
    const int h    = bh & (Hn - 1);

    // ---- theta row (h, lane): 16 fp32 = 64 B, aligned ----
    const float4* tq = reinterpret_cast<const float4*>(theta) + (size_t)(h * Kk + lane) * 4;
    float t[16];
    {
        float4 q0 = tq[0], q1 = tq[1], q2 = tq[2], q3 = tq[3];
        t[0]=q0.x; t[1]=q0.y; t[2]=q0.z; t[3]=q0.w;
        t[4]=q1.x; t[5]=q1.y; t[6]=q1.z; t[7]=q1.w;
        t[8]=q2.x; t[9]=q2.y; t[10]=q2.z; t[11]=q2.w;
        t[12]=q3.x; t[13]=q3.y; t[14]=q3.z; t[15]=q3.w;
    }

    float c = 0.0f;
    #pragma unroll
    for (int m = 2; m < 16; ++m) c = fmaf(t[m], t[m], c);

    // ---- the 8 points n = 64p + k' for this wave: exp0 of (d0,d1,0,...) ----
    const float2* ip = reinterpret_cast<const float2*>(inp) + (size_t)bh * Np + kp;
    float e0[8], e1[8];
    #pragma unroll
    for (int p = 0; p < 8; ++p) {
        float2 dd = ip[p << 6];
        float d0 = dd.x, d1 = dd.y;
        float nd = sqrtf(fmaf(d0, d0, d1 * d1));
        float nc = fmaxf(nd, EPSf);
        float ex = __expf(2.0f * nc);           // nd <= sqrt(2): no overflow
        float th = 1.0f - __fdividef(2.0f, ex + 1.0f);   // tanh(nc)
        float sc = __fdividef(th, nc);
        e0[p] = sc * d0;
        e1[p] = sc * d1;
    }

    // ---- 8 tangent terms for this lane's theta row ----
    const float t0 = t[0], t1 = t[1];
    float A = 0.0f, S0 = 0.0f, S1 = 0.0f;
    #pragma unroll
    for (int p = 0; p < 8; ++p) {
        float x0 = e0[p] + t0;
        float x1 = e1[p] + t1;
        float r  = sqrtf(fmaf(x0, x0, fmaf(x1, x1, c)));
        float rn = fmaxf(r, EPSf);
        float rc = fminf(rn, MAXN);
        float at = 0.5f * __logf(__fdividef(1.0f + rc, 1.0f - rc));  // atanh(rc)
        float a  = __fdividef(at, rn);
        A += a;
        S0 = fmaf(a, x0, S0);
        S1 = fmaf(a, x1, S1);
    }

    // ---- per-lane partial of the 16-dim sum vector ----
    float v[16];
    v[0] = S0;
    v[1] = S1;
    #pragma unroll
    for (int m = 2; m < 16; ++m) v[m] = A * t[m];

    // ---- xor-butterfly reduction across the 64 lanes (over theta rows k) ----
    #pragma unroll
    for (int off = 32; off > 0; off >>= 1) {
        #pragma unroll
        for (int m = 0; m < 16; ++m) v[m] += __shfl_xor(v[m], off, 64);
    }

    // ---- epilogue: y = g(|s|) * s ----
    float nn2 = 0.0f;
    #pragma unroll
    for (int m = 0; m < 16; ++m) nn2 = fmaf(v[m], v[m], nn2);
    float nn  = fmaxf(sqrtf(nn2), EPSf);
    float gsc = (nn < ATANH_MAX) ? 1.0f : __fdividef(ATANH_MAX, nn);

    if (lane == 0) {
        float4* op = reinterpret_cast<float4*>(out + (size_t)g * Mm);  // ((b*H+h)*K+k')*16
        op[0] = make_float4(gsc*v[0],  gsc*v[1],  gsc*v[2],  gsc*v[3]);
        op[1] = make_float4(gsc*v[4],  gsc*v[5],  gsc*v[6],  gsc*v[7]);
        op[2] = make_float4(gsc*v[8],  gsc*v[9],  gsc*v[10], gsc*v[11]);
        op[3] = make_float4(gsc*v[12], gsc*v[13], gsc*v[14], gsc*v[15]);
    }
}

extern "C" void kernel_launch(void* const* d_in, const int* in_sizes, int n_in,
                              void* d_out, int out_size, void* d_ws, size_t ws_size,
                              hipStream_t stream) {
    const float* inp   = (const float*)d_in[0];  // (64,2,512,2) fp32
    const float* theta = (const float*)d_in[1];  // (2,64,16)   fp32
    float*       out   = (float*)d_out;          // (64,2,64,16) fp32

    const int total_waves = Bsz * Hn * Kk;       // 8192
    dim3 grid(total_waves / 4), block(256);
    hipLaunchKernelGGL(PManifold_kernel, grid, block, 0, stream, inp, theta, out);
}

// Round 3
// 60.771 us; speedup vs baseline: 1.1304x; 1.1304x over previous
//
#include <hip/hip_runtime.h>

// Problem config (fixed by reference): B=64, H=2, N=512, K=64, M=16
constexpr int Bsz = 64;
constexpr int Hn  = 2;
constexpr int Np  = 512;
constexpr int Kk  = 64;
constexpr int Mm  = 16;

#define EPSf      1e-7f
#define MAXN      (1.0f - 1e-5f)
#define ATANH_MAX 6.1030338f     // atanh(1 - 1e-5)
#define HALF_LN2  0.34657359f    // 0.5 * ln(2)

// Index identity (reference's raw reshape (B,K*N,M)->(B,N,K,M)):
//   out[b,h,k'] = epilogue( sum_{k<64} sum_{p<8} tangent(point n=64p+k', theta row k) )
// Per-term (x = exp0(pad(dgm)) + theta_k, only 2 nonzero exp0 comps):
//   u = x0^2+x1^2+c_k,  c_k = sum_{m>=2} t_m^2,  rs = rsqrt(u),  r = u*rs
//   a = atanh(min(r,MAXN)) * rs = HALF_LN2 * log2((1+rc)/(1-rc)) * rs
//   per-lane partial over p: (S0, S1, A) with S=sum a*x, A=sum a; component m>=2 = A*t_m.
// Reduction: lane k -> LDS (S0,S1,A); lane (m=l&15,q=l>>4) quarter-dot with theta col m
// (mu=1 for m<2); shfl_xor 16/32 combines quarters. Epilogue exp0(log0(s)) collapses to
//   y = s if |s| < ATANH_MAX else ATANH_MAX*s/|s|.
__global__ __launch_bounds__(256) void PManifold_kernel(
    const float* __restrict__ inp,    // (B,H,N,2) fp32
    const float* __restrict__ theta,  // (H,K,M)  fp32
    float* __restrict__ out)          // (B,H,K,M) fp32
{
    __shared__ float sTheta[Kk * 17];   // stride 17: 2-way max aliasing on column reads
    __shared__ float sRed[4][196];      // per-wave: S0 @0, S1 @65, A @130 (2-way max)

    const int tid  = threadIdx.x;
    const int lane = tid & 63;                  // = theta row k
    const int wav  = tid >> 6;
    const int g    = blockIdx.x * 4 + wav;      // global wave id in [0, B*H*K)
    const int kp   = g & 63;                    // output chart index k'
    const int bh   = g >> 6;                    // b*H + h  (same for all 4 waves in block)
    const int h    = bh & (Hn - 1);

    // ---- stage theta_h into LDS (64 rows x 16, stride 17), once per block ----
    {
        const int r  = tid >> 2;                // row 0..63
        const int cb = (tid & 3) << 2;          // col base 0,4,8,12
        const float4 q = *reinterpret_cast<const float4*>(theta + (size_t)(h * Kk + r) * Mm + cb);
        sTheta[r * 17 + cb + 0] = q.x;
        sTheta[r * 17 + cb + 1] = q.y;
        sTheta[r * 17 + cb + 2] = q.z;
        sTheta[r * 17 + cb + 3] = q.w;
    }
    __syncthreads();

    // ---- theta row (h, lane): global, coalesced; keep t0,t1 and c = sum_{m>=2} t_m^2 ----
    float t0, t1, c;
    {
        const float4* tq = reinterpret_cast<const float4*>(theta) + (size_t)(h * Kk + lane) * 4;
        float4 q0 = tq[0], q1 = tq[1], q2 = tq[2], q3 = tq[3];
        t0 = q0.x; t1 = q0.y;
        c  = q0.z * q0.z + q0.w * q0.w;
        c  = fmaf(q1.x, q1.x, fmaf(q1.y, q1.y, fmaf(q1.z, q1.z, fmaf(q1.w, q1.w, c))));
        c  = fmaf(q2.x, q2.x, fmaf(q2.y, q2.y, fmaf(q2.z, q2.z, fmaf(q2.w, q2.w, c))));
        c  = fmaf(q3.x, q3.x, fmaf(q3.y, q3.y, fmaf(q3.z, q3.z, fmaf(q3.w, q3.w, c))));
    }

    // ---- exp0 of the wave's 8 points, one point per lane-group, readlane broadcast ----
    float E0, E1;
    {
        const int p = lane & 7;                 // lanes 0..7 hold the canonical copies
        const float2* ip = reinterpret_cast<const float2*>(inp) + (size_t)bh * Np;
        float2 dd = ip[(p << 6) + kp];          // point n = 64p + k'
        float nd = sqrtf(fmaf(dd.x, dd.x, dd.y * dd.y));
        float nc = fmaxf(nd, EPSf);
        float ex = __expf(2.0f * nc);           // nd <= sqrt(2): no overflow
        float th = 1.0f - __fdividef(2.0f, ex + 1.0f);   // tanh(nc)
        float sc = __fdividef(th, nc);
        E0 = sc * dd.x;
        E1 = sc * dd.y;
    }
    float e0[8], e1[8];
    #pragma unroll
    for (int p = 0; p < 8; ++p) {
        e0[p] = __int_as_float(__builtin_amdgcn_readlane(__float_as_int(E0), p));
        e1[p] = __int_as_float(__builtin_amdgcn_readlane(__float_as_int(E1), p));
    }

    // ---- 8 tangent terms for this lane's theta row (3 transcendentals/term) ----
    float At = 0.0f, S0 = 0.0f, S1 = 0.0f;
    #pragma unroll
    for (int p = 0; p < 8; ++p) {
        float x0 = e0[p] + t0;
        float x1 = e1[p] + t1;
        float u  = fmaf(x0, x0, fmaf(x1, x1, c));
        u        = fmaxf(u, 1e-14f);            // => r >= 1e-7 = EPS clamp of reference
        float rs = rsqrtf(u);                   // 1/r
        float rc = fminf(u * rs, MAXN);         // min(r, MAXN)
        float Q  = (1.0f + rc) * __fdividef(1.0f, 1.0f - rc);
        float tt = __log2f(Q) * rs;             // atanh(rc)/r = HALF_LN2 * tt
        float a  = HALF_LN2 * tt;
        At += tt;
        S0 = fmaf(a, x0, S0);
        S1 = fmaf(a, x1, S1);
    }
    const float A = HALF_LN2 * At;

    // ---- reduction: lane k publishes (S0,S1,A); quarter-dot over k ----
    sRed[wav][lane]       = S0;
    sRed[wav][65 + lane]  = S1;
    sRed[wav][130 + lane] = A;
    __syncthreads();

    const int m = lane & 15;
    const int q = lane >> 4;
    const int base = (m == 0) ? 0 : ((m == 1) ? 65 : 130);
    float acc = 0.0f;
    #pragma unroll
    for (int j = 0; j < 16; ++j) {
        int   k   = (q << 4) + j;
        float val = sRed[wav][base + k];        // S0_k / S1_k / A_k per this lane's m
        float mu  = sTheta[k * 17 + m];         // theta[k][m]
        mu = (m < 2) ? 1.0f : mu;
        acc = fmaf(val, mu, acc);
    }
    // combine the 4 quarters -> full sum component in every lane
    acc += __shfl_xor(acc, 16, 64);
    acc += __shfl_xor(acc, 32, 64);

    // ---- epilogue: y = g(|s|) * s ----
    float w = acc * acc;
    #pragma unroll
    for (int off = 1; off < 16; off <<= 1) w += __shfl_xor(w, off, 64);
    float nn  = fmaxf(sqrtf(w), EPSf);
    float gsc = (nn < ATANH_MAX) ? 1.0f : __fdividef(ATANH_MAX, nn);

    if (lane < 16) {
        out[(size_t)g * Mm + m] = gsc * acc;    // 16 lanes x 4B, coalesced 64B
    }
}

extern "C" void kernel_launch(void* const* d_in, const int* in_sizes, int n_in,
                              void* d_out, int out_size, void* d_ws, size_t ws_size,
                              hipStream_t stream) {
    const float* inp   = (const float*)d_in[0];  // (64,2,512,2) fp32
    const float* theta = (const float*)d_in[1];  // (2,64,16)   fp32
    float*       out   = (float*)d_out;          // (64,2,64,16) fp32

    const int total_waves = Bsz * Hn * Kk;       // 8192
    dim3 grid(total_waves / 4), block(256);
    hipLaunchKernelGGL(PManifold_kernel, grid, block, 0, stream, inp, theta, out);
}